// Round 2
// baseline (266.098 us; speedup 1.0000x reference)
//
#include <hip/hip_runtime.h>

// out[i][d] = params[idx[i]] * xs[i][d];  N=4194304, D=8, V=1048576
//
// Latency-bound gather-scale. One thread per ROW (D=8 floats = 2 float4),
// 4 rows per thread strided by total thread count:
//  - 4 independent idx->params gather chains in flight per thread (4x MLP)
//  - idx loaded once per row (was 2x)
//  - non-temporal loads/stores for streaming xs/idx/out keep the 4 MB
//    params table resident in each XCD's 4 MB L2 (gathers stay L2 hits)
//
// NOTE: out_size from the harness is in ELEMENTS (floats), not bytes.
// nrows = out_size / 8 (D=8 floats per row).

typedef float f32x4 __attribute__((ext_vector_type(4)));

__global__ __launch_bounds__(256) void spvar_kernel(
    const f32x4* __restrict__ xs4,
    const int*   __restrict__ idx,
    const float* __restrict__ params,
    f32x4*       __restrict__ out4,
    int nrows, int stride)   // stride = gridDim.x * blockDim.x
{
    const int t = blockIdx.x * blockDim.x + threadIdx.x;
    const int r0 = t;
    const int r1 = t + stride;
    const int r2 = t + 2 * stride;
    const int r3 = t + 3 * stride;

    if (r3 < nrows) {
        // ---- fast path: all 4 rows valid, batch everything ----
        const int i0 = __builtin_nontemporal_load(idx + r0);
        const int i1 = __builtin_nontemporal_load(idx + r1);
        const int i2 = __builtin_nontemporal_load(idx + r2);
        const int i3 = __builtin_nontemporal_load(idx + r3);

        const float p0 = params[i0];
        const float p1 = params[i1];
        const float p2 = params[i2];
        const float p3 = params[i3];

        f32x4 a0 = __builtin_nontemporal_load(xs4 + 2 * r0);
        f32x4 b0 = __builtin_nontemporal_load(xs4 + 2 * r0 + 1);
        f32x4 a1 = __builtin_nontemporal_load(xs4 + 2 * r1);
        f32x4 b1 = __builtin_nontemporal_load(xs4 + 2 * r1 + 1);
        f32x4 a2 = __builtin_nontemporal_load(xs4 + 2 * r2);
        f32x4 b2 = __builtin_nontemporal_load(xs4 + 2 * r2 + 1);
        f32x4 a3 = __builtin_nontemporal_load(xs4 + 2 * r3);
        f32x4 b3 = __builtin_nontemporal_load(xs4 + 2 * r3 + 1);

        a0 *= p0; b0 *= p0;
        a1 *= p1; b1 *= p1;
        a2 *= p2; b2 *= p2;
        a3 *= p3; b3 *= p3;

        __builtin_nontemporal_store(a0, out4 + 2 * r0);
        __builtin_nontemporal_store(b0, out4 + 2 * r0 + 1);
        __builtin_nontemporal_store(a1, out4 + 2 * r1);
        __builtin_nontemporal_store(b1, out4 + 2 * r1 + 1);
        __builtin_nontemporal_store(a2, out4 + 2 * r2);
        __builtin_nontemporal_store(b2, out4 + 2 * r2 + 1);
        __builtin_nontemporal_store(a3, out4 + 2 * r3);
        __builtin_nontemporal_store(b3, out4 + 2 * r3 + 1);
    } else {
        // ---- tail: per-row bounds check (only last partial chunk) ----
        #pragma unroll
        for (int u = 0; u < 4; ++u) {
            const int r = t + u * stride;
            if (r < nrows) {
                const float p = params[idx[r]];
                f32x4 a = __builtin_nontemporal_load(xs4 + 2 * r);
                f32x4 b = __builtin_nontemporal_load(xs4 + 2 * r + 1);
                a *= p; b *= p;
                __builtin_nontemporal_store(a, out4 + 2 * r);
                __builtin_nontemporal_store(b, out4 + 2 * r + 1);
            }
        }
    }
}

extern "C" void kernel_launch(void* const* d_in, const int* in_sizes, int n_in,
                              void* d_out, int out_size, void* d_ws, size_t ws_size,
                              hipStream_t stream) {
    const float* xs     = (const float*)d_in[0];   // [N, 8] f32
    const int*   idx    = (const int*)d_in[1];     // [N] int32 (jax x64 off)
    const float* params = (const float*)d_in[2];   // [V, 1] f32

    const int nrows = out_size / 8;                // N  (out_size is in f32 ELEMENTS, D=8)
    const int block = 256;
    const int rows_per_thread = 4;
    const int grid = (nrows + block * rows_per_thread - 1) / (block * rows_per_thread);
    const int stride = grid * block;

    spvar_kernel<<<grid, block, 0, stream>>>(
        (const f32x4*)xs, idx, params, (f32x4*)d_out, nrows, stride);
}